// Round 1
// 365.586 us; speedup vs baseline: 1.0922x; 1.0922x over previous
//
#include <hip/hip_runtime.h>

#define NSEQ   4096
#define TSTEPS 512
#define FIN    5
#define HID    64
#define SPB    16     // sequences per block (MFMA M)
#define BLK    512    // 8 waves: w0-3 "G" (gate MFMA + epilogue), w4-7 "E" (x-proj seed + staging)

// Neutral names — do NOT reuse HIP vector-type names like short8 (R4 crash)
typedef __attribute__((ext_vector_type(8))) short bsh8;    // 8 bf16 in 4 VGPRs
typedef __attribute__((ext_vector_type(4))) float f32x4;   // MFMA accumulator
typedef __attribute__((ext_vector_type(4))) int   i32x4;

#define MFMA16(A, B, C) __builtin_amdgcn_mfma_f32_16x16x32_bf16((A), (B), (C), 0, 0, 0)

// R7: gate pre-scaling folded into weights/biases so MFMA output is exp2-ready.
//   i,f,o rows scaled by -log2e  -> sigmoid = rcp(1 + exp2(m))
//   g rows scaled by +2*log2e    -> tanh    = 1 - 2*rcp(1 + exp2(p))
//   c tracked as cs = 2*log2e*c  -> tanh(c) = 1 - 2*rcp(1 + exp2(cs))
#define LOG2E 1.4426950408889634f
#define SNEG  (-LOG2E)
#define SPOS  (2.0f * LOG2E)

struct Frag2 { bsh8 hi; bsh8 lo; };

__device__ __forceinline__ unsigned short bf16hi_rn(float x) {
    unsigned u = __float_as_uint(x);
    return (unsigned short)((u + 0x7fffu + ((u >> 16) & 1u)) >> 16);
}
__device__ __forceinline__ void split_bf16(float v, unsigned short& h, unsigned short& l) {
    h = bf16hi_rn(v);
    float hf_ = __uint_as_float(((unsigned)h) << 16);
    l = bf16hi_rn(v - hf_);
}
__device__ __forceinline__ float rcp1pexp2(float x) {   // 1/(1 + 2^x): exp2, add, rcp (3 instrs)
    return __builtin_amdgcn_rcpf(1.0f + __builtin_amdgcn_exp2f(x));
}

// Whh B-fragment, SPLIT hi/lo, pre-scaled per gate (scale applied before split)
__device__ __forceinline__ Frag2 load_whh_frag(const float* __restrict__ Whh, int row, int k, float scale) {
    const float* p = Whh + row * HID + k;
    Frag2 r;
#pragma unroll
    for (int j = 0; j < 8; ++j) {
        unsigned short h, l;
        split_bf16(scale * p[j], h, l);
        r.hi[j] = (short)h; r.lo[j] = (short)l;
    }
    return r;
}
// Wih B-fragment with bias folded into k-slot FIN (A carries 1.0 there)
__device__ __forceinline__ Frag2 load_wih_frag(const float* __restrict__ Wih,
                                               const float* __restrict__ bih,
                                               const float* __restrict__ bhh,
                                               int row, int quad, float scale) {
    Frag2 r;
#pragma unroll
    for (int j = 0; j < 8; ++j) { r.hi[j] = 0; r.lo[j] = 0; }
    if (quad == 0) {
        unsigned short h, l;
#pragma unroll
        for (int j = 0; j < FIN; ++j) {
            split_bf16(scale * Wih[row * FIN + j], h, l);
            r.hi[j] = (short)h; r.lo[j] = (short)l;
        }
        split_bf16(scale * (bih[row] + bhh[row]), h, l);
        r.hi[FIN] = (short)h; r.lo[FIN] = (short)l;
    }
    return r;
}

// stage one 64-step x chunk (bf16-hi, 1.0 in bias slot) into dst[64][SPB] — E-waves (256 thr)
__device__ __forceinline__ void stage_chunk(const float* __restrict__ feat,
                                            bsh8 (*dst)[SPB],
                                            int seq0, int t0, int tidE) {
#pragma unroll
    for (int it = 0; it < (64 * SPB) / 256; ++it) {
        int idx = tidE + it * 256;
        int t2  = idx >> 4;
        int s   = idx & 15;
        const float* xp = feat + (size_t)(seq0 + s) * (TSTEPS * FIN) + (t0 + t2) * FIN;
        bsh8 v = {0, 0, 0, 0, 0, 0, 0, 0};
#pragma unroll
        for (int j = 0; j < FIN; ++j) v[j] = (short)bf16hi_rn(xp[j]);
        v[FIN] = (short)0x3F80;   // bf16(1.0) -> bias k-slot
        dst[t2][s] = v;
    }
}

// R7 structure: wave-specialized producer/consumer.
//  G-waves (tid<256): per step: read acc seed (x·Wih+b) from LDS, 16 h-MFMAs,
//    exp2-native epilogue (10 trans/elem, minimal regular VALU), cvt_pk h-write.
//  E-waves (tid>=256): per step: compute seed(t+1) via 8 x-MFMAs into seedb[(t+1)&1],
//    stage x chunks. Both loops execute exactly one s_barrier per step (counts match).
//  seedb is parity double-buffered: G reads [t&1] while E writes [(t+1)&1] — no race.
__global__ __launch_bounds__(BLK)
void lstm_kernel(const float* __restrict__ feat,
                 const float* __restrict__ Wih,
                 const float* __restrict__ Whh,
                 const float* __restrict__ bih,
                 const float* __restrict__ bhh,
                 const float* __restrict__ Wd,
                 const float* __restrict__ bd,
                 float* __restrict__ pred,
                 float* __restrict__ accums) {
    __shared__ bsh8  aA[2][SPB][9];                        // h bf16-hi, double-buffered
    __shared__ bsh8  xb[2][64][SPB];                       // x chunks (32 KB)
    __shared__ __align__(16) float seedb[2][4][HID][SPB];  // x·Wih+b seed, dbuf (32 KB)
    __shared__ float hf[SPB][HID + 1];                     // final h fp32
    __shared__ float pf[SPB][17];                          // pred partials

    const int tid   = threadIdx.x;
    const int w     = tid >> 6;
    const int lane  = tid & 63;
    const int col   = lane & 15;       // MFMA col / A-row (seq)
    const int quad  = lane >> 4;
    const int quad4 = quad * 4;
    const int seq0  = blockIdx.x * SPB;

    if (blockIdx.x == 0 && tid < 4) accums[tid] = 0.0f;

    {
        bsh8 z = {0, 0, 0, 0, 0, 0, 0, 0};
        if (tid < SPB * 9) (&aA[0][0][0])[tid] = z;        // h(-1) = 0
    }
    if (w >= 4) stage_chunk(feat, xb[0], seq0, 0, tid - 256);
    __syncthreads();

    if (w < 4) {
        // ---------------- G-waves: serial LSTM path ----------------
        const int u = 16 * w + col;
        const Frag2 b00 = load_whh_frag(Whh, 0*HID + u,      quad*8, SNEG);
        const Frag2 b01 = load_whh_frag(Whh, 0*HID + u, 32 + quad*8, SNEG);
        const Frag2 b10 = load_whh_frag(Whh, 1*HID + u,      quad*8, SNEG);
        const Frag2 b11 = load_whh_frag(Whh, 1*HID + u, 32 + quad*8, SNEG);
        const Frag2 b20 = load_whh_frag(Whh, 2*HID + u,      quad*8, SPOS);
        const Frag2 b21 = load_whh_frag(Whh, 2*HID + u, 32 + quad*8, SPOS);
        const Frag2 b30 = load_whh_frag(Whh, 3*HID + u,      quad*8, SNEG);
        const Frag2 b31 = load_whh_frag(Whh, 3*HID + u, 32 + quad*8, SNEG);

        float cs_[4] = {0.f, 0.f, 0.f, 0.f};   // c in 2*log2e scale
        __builtin_amdgcn_s_setprio(1);          // T5: favor the critical wave

        for (int t = 0; t < TSTEPS; ++t) {
            const int buf = t & 1;
            const int nb  = buf ^ 1;
            __syncthreads();   // h(t-1) + seed(t) visible

            f32x4 acc0 = *(const f32x4*)&seedb[buf][0][u][quad4];
            f32x4 acc1 = *(const f32x4*)&seedb[buf][1][u][quad4];
            f32x4 acc2 = *(const f32x4*)&seedb[buf][2][u][quad4];
            f32x4 acc3 = *(const f32x4*)&seedb[buf][3][u][quad4];
            bsh8 ah0 = aA[buf][col][quad];
            bsh8 ah1 = aA[buf][col][4 + quad];

            acc0 = MFMA16(ah0, b00.hi, acc0); acc0 = MFMA16(ah1, b01.hi, acc0);
            acc1 = MFMA16(ah0, b10.hi, acc1); acc1 = MFMA16(ah1, b11.hi, acc1);
            acc2 = MFMA16(ah0, b20.hi, acc2); acc2 = MFMA16(ah1, b21.hi, acc2);
            acc3 = MFMA16(ah0, b30.hi, acc3); acc3 = MFMA16(ah1, b31.hi, acc3);
            acc0 = MFMA16(ah0, b00.lo, acc0); acc0 = MFMA16(ah1, b01.lo, acc0);
            acc1 = MFMA16(ah0, b10.lo, acc1); acc1 = MFMA16(ah1, b11.lo, acc1);
            acc2 = MFMA16(ah0, b20.lo, acc2); acc2 = MFMA16(ah1, b21.lo, acc2);
            acc3 = MFMA16(ah0, b30.lo, acc3); acc3 = MFMA16(ah1, b31.lo, acc3);

            // C/D layout: col=lane&15 (unit), row=quad*4+r (seq)
            float hh_[4];
#pragma unroll
            for (int r = 0; r < 4; ++r) {
                float si  = rcp1pexp2(acc0[r]);                       // sigmoid(i)
                float sf  = rcp1pexp2(acc1[r]);                       // sigmoid(f)
                float rg  = rcp1pexp2(acc2[r]);                       // 1/(1+e^{2zg})
                float so  = rcp1pexp2(acc3[r]);                       // sigmoid(o)
                float tgK = __builtin_fmaf(-2.0f * SPOS, rg, SPOS);   // 2log2e * tanh(zg)
                cs_[r] = __builtin_fmaf(sf, cs_[r], si * tgK);
                float rc  = rcp1pexp2(cs_[r]);
                float t2  = so * rc;
                hh_[r] = __builtin_fmaf(-2.0f, t2, so);               // o * tanh(c)
            }
            // RNE bf16 pack, 2 floats/instr (T12: dst.lo = src0)
            unsigned pk01, pk23;
            asm("v_cvt_pk_bf16_f32 %0, %1, %2" : "=v"(pk01) : "v"(hh_[0]), "v"(hh_[1]));
            asm("v_cvt_pk_bf16_f32 %0, %1, %2" : "=v"(pk23) : "v"(hh_[2]), "v"(hh_[3]));
            unsigned short* hp = (unsigned short*)&aA[nb][quad4][0] + u;  // row pitch 72 shorts
            hp[0]   = (unsigned short)pk01;
            hp[72]  = (unsigned short)(pk01 >> 16);
            hp[144] = (unsigned short)pk23;
            hp[216] = (unsigned short)(pk23 >> 16);
            if (t == TSTEPS - 1) {
                hf[quad4 + 0][u] = hh_[0];
                hf[quad4 + 1][u] = hh_[1];
                hf[quad4 + 2][u] = hh_[2];
                hf[quad4 + 3][u] = hh_[3];
            }
        }
        __builtin_amdgcn_s_setprio(0);
    } else {
        // ---------------- E-waves: x-projection seed + staging ----------------
        const int wE   = w - 4;
        const int uE   = 16 * wE + col;
        const int tidE = tid - 256;
        const Frag2 w0 = load_wih_frag(Wih, bih, bhh, 0*HID + uE, quad, SNEG);
        const Frag2 w1 = load_wih_frag(Wih, bih, bhh, 1*HID + uE, quad, SNEG);
        const Frag2 w2 = load_wih_frag(Wih, bih, bhh, 2*HID + uE, quad, SPOS);
        const Frag2 w3 = load_wih_frag(Wih, bih, bhh, 3*HID + uE, quad, SNEG);

        {   // seed(0) — before first in-loop barrier, so G's t=0 read is ordered after it
            bsh8 ax = xb[0][0][col];
            f32x4 e0 = {0.f,0.f,0.f,0.f}, e1 = e0, e2 = e0, e3 = e0;
            e0 = MFMA16(ax, w0.hi, e0); e0 = MFMA16(ax, w0.lo, e0);
            e1 = MFMA16(ax, w1.hi, e1); e1 = MFMA16(ax, w1.lo, e1);
            e2 = MFMA16(ax, w2.hi, e2); e2 = MFMA16(ax, w2.lo, e2);
            e3 = MFMA16(ax, w3.hi, e3); e3 = MFMA16(ax, w3.lo, e3);
            *(f32x4*)&seedb[0][0][uE][quad4] = e0;
            *(f32x4*)&seedb[0][1][uE][quad4] = e1;
            *(f32x4*)&seedb[0][2][uE][quad4] = e2;
            *(f32x4*)&seedb[0][3][uE][quad4] = e3;
        }
        for (int t = 0; t < TSTEPS; ++t) {
            __syncthreads();   // matches G's per-step barrier
            if ((t & 63) == 0 && t + 64 < TSTEPS)
                stage_chunk(feat, xb[((t >> 6) + 1) & 1], seq0, ((t >> 6) + 1) * 64, tidE);
            if (t + 1 < TSTEPS) {
                const int t1 = t + 1;
                bsh8 ax = xb[(t1 >> 6) & 1][t1 & 63][col];
                f32x4 e0 = {0.f,0.f,0.f,0.f}, e1 = e0, e2 = e0, e3 = e0;
                e0 = MFMA16(ax, w0.hi, e0); e0 = MFMA16(ax, w0.lo, e0);
                e1 = MFMA16(ax, w1.hi, e1); e1 = MFMA16(ax, w1.lo, e1);
                e2 = MFMA16(ax, w2.hi, e2); e2 = MFMA16(ax, w2.lo, e2);
                e3 = MFMA16(ax, w3.hi, e3); e3 = MFMA16(ax, w3.lo, e3);
                const int sb = t1 & 1;
                *(f32x4*)&seedb[sb][0][uE][quad4] = e0;
                *(f32x4*)&seedb[sb][1][uE][quad4] = e1;
                *(f32x4*)&seedb[sb][2][uE][quad4] = e2;
                *(f32x4*)&seedb[sb][3][uE][quad4] = e3;
            }
        }
    }
    __syncthreads();   // hf visible; E done

    // ---- fused pred head: pred = leaky_relu(h @ Wd^T + bd) ----
    if (tid < 256) {
        int s  = tid & 15;
        int hq = tid >> 4;           // 16 unit-groups of 4
        int j0 = hq * 4;
        float part = hf[s][j0] * Wd[j0] + hf[s][j0 + 1] * Wd[j0 + 1]
                   + hf[s][j0 + 2] * Wd[j0 + 2] + hf[s][j0 + 3] * Wd[j0 + 3];
        pf[s][hq] = part;
    }
    __syncthreads();
    if (tid < SPB) {
        float sum = bd[0];
#pragma unroll
        for (int j = 0; j < 16; ++j) sum += pf[tid][j];
        float p = (sum >= 0.0f) ? sum : 0.2f * sum;
        pred[seq0 + tid] = p;
    }
}

// fused losses: grid 512 (2 blocks/CU), 8 i-rows per block, f32x4 LDS reads.
// block 0 additionally does the masked-MSE partials.
__global__ __launch_bounds__(256)
void loss_kernel(const float* __restrict__ pred,
                 const float* __restrict__ ret,
                 const int* __restrict__ mask,
                 float* __restrict__ accums) {
    __shared__ __align__(16) float sp[NSEQ];
    __shared__ __align__(16) float sg[NSEQ];
    __shared__ __align__(16) float sq[NSEQ];
    __shared__ float wsum[8];
    int tid = threadIdx.x;
    for (int idx = tid; idx < NSEQ / 4; idx += 256) {
        f32x4 p4 = ((const f32x4*)pred)[idx];
        f32x4 g4 = ((const f32x4*)ret)[idx];
        i32x4 m4 = ((const i32x4*)mask)[idx];
        f32x4 q4;
#pragma unroll
        for (int l = 0; l < 4; ++l) q4[l] = m4[l] ? 1.0f : 0.0f;
        *(f32x4*)&sp[idx * 4] = p4;
        *(f32x4*)&sg[idx * 4] = g4;
        *(f32x4*)&sq[idx * 4] = q4;
    }
    __syncthreads();

    if (blockIdx.x == 0) {   // regression loss partials
        float v = 0.0f, m = 0.0f;
        for (int j = tid; j < NSEQ; j += 256) {
            float mj = sq[j];
            float d  = sp[j] - sg[j];
            v += d * d * mj;
            m += mj;
        }
#pragma unroll
        for (int off = 32; off > 0; off >>= 1) {
            v += __shfl_down(v, off, 64);
            m += __shfl_down(m, off, 64);
        }
        if ((tid & 63) == 0) {
            atomicAdd(&accums[0], v);
            atomicAdd(&accums[1], m);
        }
    }

    int iloc = tid >> 5;          // 8 rows per block
    int jp   = tid & 31;          // 32 lanes per row
    int i    = blockIdx.x * 8 + iloc;
    float pi = sp[i], gi = sg[i], qi = sq[i];
    float sum = 0.0f;
    for (int j0 = jp * 4; j0 < NSEQ; j0 += 128) {
        f32x4 p4 = *(const f32x4*)&sp[j0];
        f32x4 g4 = *(const f32x4*)&sg[j0];
        f32x4 q4 = *(const f32x4*)&sq[j0];
#pragma unroll
        for (int l = 0; l < 4; ++l) {
            float t = -(p4[l] - pi) * (g4[l] - gi);
            sum += fmaxf(t, 0.0f) * q4[l];
        }
    }
    sum *= qi;
#pragma unroll
    for (int off = 16; off > 0; off >>= 1) sum += __shfl_down(sum, off, 32);
    if (jp == 0) wsum[iloc] = sum;
    __syncthreads();
    if (tid == 0) {
        float s = wsum[0] + wsum[1] + wsum[2] + wsum[3]
                + wsum[4] + wsum[5] + wsum[6] + wsum[7];
        atomicAdd(&accums[2], s);
    }
}

__global__ void final_kernel(const float* __restrict__ accums,
                             float* __restrict__ out) {
    float reg  = accums[0] / (accums[1] + 1e-8f);
    float rank = accums[2] / 16777216.0f;   // N*N
    out[NSEQ + 0] = reg + rank;
    out[NSEQ + 1] = reg;
    out[NSEQ + 2] = rank;
}

extern "C" void kernel_launch(void* const* d_in, const int* in_sizes, int n_in,
                              void* d_out, int out_size, void* d_ws, size_t ws_size,
                              hipStream_t stream) {
    const float* feat = (const float*)d_in[0];
    const float* ret  = (const float*)d_in[1];
    const int*   mask = (const int*)d_in[2];
    const float* Wih  = (const float*)d_in[3];
    const float* Whh  = (const float*)d_in[4];
    const float* bih  = (const float*)d_in[5];
    const float* bhh  = (const float*)d_in[6];
    const float* Wd   = (const float*)d_in[7];
    const float* bd   = (const float*)d_in[8];
    float* out    = (float*)d_out;
    float* accums = (float*)d_ws;            // [0..3] loss partials

    lstm_kernel<<<NSEQ / SPB, BLK, 0, stream>>>(feat, Wih, Whh, bih, bhh,
                                                Wd, bd, out, accums);
    loss_kernel<<<NSEQ / 8, 256, 0, stream>>>(out, ret, mask, accums);
    final_kernel<<<1, 1, 0, stream>>>(accums, out);
}

// Round 2
// 351.075 us; speedup vs baseline: 1.1373x; 1.0413x over previous
//
#include <hip/hip_runtime.h>

#define NSEQ   4096
#define TSTEPS 512
#define FIN    5
#define HID    64
#define SPB    16     // sequences per block (MFMA M)
#define BLK    512    // 8 waves: w0-3 "G" (gate MFMA + epilogue), w4-7 "E" (x-proj seed + staging)

// Neutral names — do NOT reuse HIP vector-type names like short8 (R4 crash)
typedef __attribute__((ext_vector_type(8))) short bsh8;    // 8 bf16 in 4 VGPRs
typedef __attribute__((ext_vector_type(4))) float f32x4;   // MFMA accumulator
typedef __attribute__((ext_vector_type(4))) int   i32x4;

#define MFMA16(A, B, C) __builtin_amdgcn_mfma_f32_16x16x32_bf16((A), (B), (C), 0, 0, 0)

// Gate pre-scaling folded into weights/biases so MFMA output is exp2-ready.
//   i,f,o rows scaled by -log2e  -> sigmoid = rcp(1 + exp2(m))
//   g rows scaled by +2*log2e    -> tanh    = (Eg-1)/(Eg+1)
//   c tracked as cs = 2*log2e*c  -> tanh(c) = (Ec-1)/(Ec+1)
#define LOG2E 1.4426950408889634f
#define SNEG  (-LOG2E)
#define SPOS  (2.0f * LOG2E)

struct Frag2 { bsh8 hi; bsh8 lo; };

__device__ __forceinline__ unsigned short bf16hi_rn(float x) {
    unsigned u = __float_as_uint(x);
    return (unsigned short)((u + 0x7fffu + ((u >> 16) & 1u)) >> 16);
}
__device__ __forceinline__ void split_bf16(float v, unsigned short& h, unsigned short& l) {
    h = bf16hi_rn(v);
    float hf_ = __uint_as_float(((unsigned)h) << 16);
    l = bf16hi_rn(v - hf_);
}

// Whh B-fragment, SPLIT hi/lo, pre-scaled per gate (scale applied before split)
__device__ __forceinline__ Frag2 load_whh_frag(const float* __restrict__ Whh, int row, int k, float scale) {
    const float* p = Whh + row * HID + k;
    Frag2 r;
#pragma unroll
    for (int j = 0; j < 8; ++j) {
        unsigned short h, l;
        split_bf16(scale * p[j], h, l);
        r.hi[j] = (short)h; r.lo[j] = (short)l;
    }
    return r;
}
// Wih B-fragment with bias folded into k-slot FIN (A carries 1.0 there)
__device__ __forceinline__ Frag2 load_wih_frag(const float* __restrict__ Wih,
                                               const float* __restrict__ bih,
                                               const float* __restrict__ bhh,
                                               int row, int quad, float scale) {
    Frag2 r;
#pragma unroll
    for (int j = 0; j < 8; ++j) { r.hi[j] = 0; r.lo[j] = 0; }
    if (quad == 0) {
        unsigned short h, l;
#pragma unroll
        for (int j = 0; j < FIN; ++j) {
            split_bf16(scale * Wih[row * FIN + j], h, l);
            r.hi[j] = (short)h; r.lo[j] = (short)l;
        }
        split_bf16(scale * (bih[row] + bhh[row]), h, l);
        r.hi[FIN] = (short)h; r.lo[FIN] = (short)l;
    }
    return r;
}

// stage one 64-step x chunk (bf16-hi, 1.0 in bias slot) into dst[64][SPB] — E-waves (256 thr)
__device__ __forceinline__ void stage_chunk(const float* __restrict__ feat,
                                            bsh8 (*dst)[SPB],
                                            int seq0, int t0, int tidE) {
#pragma unroll
    for (int it = 0; it < (64 * SPB) / 256; ++it) {
        int idx = tidE + it * 256;
        int t2  = idx >> 4;
        int s   = idx & 15;
        const float* xp = feat + (size_t)(seq0 + s) * (TSTEPS * FIN) + (t0 + t2) * FIN;
        bsh8 v = {0, 0, 0, 0, 0, 0, 0, 0};
#pragma unroll
        for (int j = 0; j < FIN; ++j) v[j] = (short)bf16hi_rn(xp[j]);
        v[FIN] = (short)0x3F80;   // bf16(1.0) -> bias k-slot
        dst[t2][s] = v;
    }
}

// Wave-specialized producer/consumer LSTM.
//  G-waves (tid<256): 16 h-MFMAs from C=0, add LDS seed (x·Wih+b), exp2-native
//    epilogue (8 trans/elem via rcp-merge), cvt_pk h-write.
//  E-waves (tid>=256): seed(t+1) via 8 x-MFMAs into seedb[(t+1)&1], x staging.
//  seedb layout [2][wave][gate][lane] is a per-lane-linear wave-to-wave mailbox
//  (E lane (col,quad) produces exactly what G lane (col,quad) consumes) —
//  lane l accesses byte l*16: every 8-lane phase covers all 32 banks (R2 fix;
//  the old [g][u][quad4] layout was ~4-way conflicted: 62.9M conflict cycles).
__global__ __launch_bounds__(BLK)
void lstm_kernel(const float* __restrict__ feat,
                 const float* __restrict__ Wih,
                 const float* __restrict__ Whh,
                 const float* __restrict__ bih,
                 const float* __restrict__ bhh,
                 const float* __restrict__ Wd,
                 const float* __restrict__ bd,
                 float* __restrict__ pred,
                 float* __restrict__ accums) {
    __shared__ bsh8  aA[2][SPB][9];                        // h bf16-hi, double-buffered
    __shared__ bsh8  xb[2][64][SPB];                       // x chunks (32 KB, E-only)
    __shared__ __align__(16) f32x4 seedb[2][4][4][64];     // [parity][wave][gate][lane] (32 KB)
    __shared__ float hf[SPB][HID + 1];                     // final h fp32
    __shared__ float pf[SPB][17];                          // pred partials

    const int tid   = threadIdx.x;
    const int w     = tid >> 6;
    const int lane  = tid & 63;
    const int col   = lane & 15;       // MFMA col / A-row (seq)
    const int quad  = lane >> 4;
    const int quad4 = quad * 4;
    const int seq0  = blockIdx.x * SPB;

    if (blockIdx.x == 0 && tid < 4) accums[tid] = 0.0f;

    {
        bsh8 z = {0, 0, 0, 0, 0, 0, 0, 0};
        if (tid < SPB * 9) (&aA[0][0][0])[tid] = z;        // h(-1) = 0
    }
    if (w >= 4) stage_chunk(feat, xb[0], seq0, 0, tid - 256);
    __syncthreads();

    if (w < 4) {
        // ---------------- G-waves: serial LSTM path ----------------
        const int u = 16 * w + col;
        const Frag2 b00 = load_whh_frag(Whh, 0*HID + u,      quad*8, SNEG);
        const Frag2 b01 = load_whh_frag(Whh, 0*HID + u, 32 + quad*8, SNEG);
        const Frag2 b10 = load_whh_frag(Whh, 1*HID + u,      quad*8, SNEG);
        const Frag2 b11 = load_whh_frag(Whh, 1*HID + u, 32 + quad*8, SNEG);
        const Frag2 b20 = load_whh_frag(Whh, 2*HID + u,      quad*8, SPOS);
        const Frag2 b21 = load_whh_frag(Whh, 2*HID + u, 32 + quad*8, SPOS);
        const Frag2 b30 = load_whh_frag(Whh, 3*HID + u,      quad*8, SNEG);
        const Frag2 b31 = load_whh_frag(Whh, 3*HID + u, 32 + quad*8, SNEG);

        float cs_[4] = {0.f, 0.f, 0.f, 0.f};   // c in 2*log2e scale
        __builtin_amdgcn_s_setprio(1);          // T5: favor the critical wave

        for (int t = 0; t < TSTEPS; ++t) {
            const int buf = t & 1;
            const int nb  = buf ^ 1;
            __syncthreads();   // h(t-1) + seed(t) visible

            bsh8 ah0 = aA[buf][col][quad];
            bsh8 ah1 = aA[buf][col][4 + quad];
            // seed reads issue here; consumed only AFTER the MFMA block (C=0
            // start) so their latency hides under ~80 cyc of MFMA issue.
            f32x4 s0 = seedb[buf][w][0][lane];
            f32x4 s1 = seedb[buf][w][1][lane];
            f32x4 s2 = seedb[buf][w][2][lane];
            f32x4 s3 = seedb[buf][w][3][lane];

            const f32x4 zz = {0.f, 0.f, 0.f, 0.f};
            f32x4 acc0 = MFMA16(ah0, b00.hi, zz);
            f32x4 acc1 = MFMA16(ah0, b10.hi, zz);
            f32x4 acc2 = MFMA16(ah0, b20.hi, zz);
            f32x4 acc3 = MFMA16(ah0, b30.hi, zz);
            acc0 = MFMA16(ah1, b01.hi, acc0);
            acc1 = MFMA16(ah1, b11.hi, acc1);
            acc2 = MFMA16(ah1, b21.hi, acc2);
            acc3 = MFMA16(ah1, b31.hi, acc3);
            acc0 = MFMA16(ah0, b00.lo, acc0);
            acc1 = MFMA16(ah0, b10.lo, acc1);
            acc2 = MFMA16(ah0, b20.lo, acc2);
            acc3 = MFMA16(ah0, b30.lo, acc3);
            acc0 = MFMA16(ah1, b01.lo, acc0);
            acc1 = MFMA16(ah1, b11.lo, acc1);
            acc2 = MFMA16(ah1, b21.lo, acc2);
            acc3 = MFMA16(ah1, b31.lo, acc3);
            acc0 = acc0 + s0;
            acc1 = acc1 + s1;
            acc2 = acc2 + s2;
            acc3 = acc3 + s3;

            // C/D layout: col=lane&15 (unit), row=quad*4+r (seq)
            // 8 trans/elem: 5 exp2 + 3 rcp (sigmoid·tanh pairs share one rcp)
            float hh_[4];
#pragma unroll
            for (int r = 0; r < 4; ++r) {
                float Ei = __builtin_amdgcn_exp2f(acc0[r]);   // e^{-zi}
                float Ef = __builtin_amdgcn_exp2f(acc1[r]);   // e^{-zf}
                float Eg = __builtin_amdgcn_exp2f(acc2[r]);   // e^{+2zg}
                float Eo = __builtin_amdgcn_exp2f(acc3[r]);   // e^{-zo}
                float R1 = __builtin_amdgcn_rcpf((1.0f + Ei) * (1.0f + Eg));
                float sf = __builtin_amdgcn_rcpf(1.0f + Ef);
                float n1 = __builtin_fmaf(SPOS, Eg, -SPOS);   // SPOS*(Eg-1)
                cs_[r] = __builtin_fmaf(sf, cs_[r], n1 * R1); // sf*cs + SPOS*si*tanh(zg)
                float Ec = __builtin_amdgcn_exp2f(cs_[r]);    // e^{+2c}
                float R2 = __builtin_amdgcn_rcpf((1.0f + Eo) * (1.0f + Ec));
                hh_[r] = (Ec - 1.0f) * R2;                    // so * tanh(c)
            }
            // RNE bf16 pack, 2 floats/instr (T12: dst.lo = src0)
            unsigned pk01, pk23;
            asm("v_cvt_pk_bf16_f32 %0, %1, %2" : "=v"(pk01) : "v"(hh_[0]), "v"(hh_[1]));
            asm("v_cvt_pk_bf16_f32 %0, %1, %2" : "=v"(pk23) : "v"(hh_[2]), "v"(hh_[3]));
            unsigned short* hp = (unsigned short*)&aA[nb][quad4][0] + u;  // row pitch 72 shorts
            hp[0]   = (unsigned short)pk01;
            hp[72]  = (unsigned short)(pk01 >> 16);
            hp[144] = (unsigned short)pk23;
            hp[216] = (unsigned short)(pk23 >> 16);
            if (t == TSTEPS - 1) {
                hf[quad4 + 0][u] = hh_[0];
                hf[quad4 + 1][u] = hh_[1];
                hf[quad4 + 2][u] = hh_[2];
                hf[quad4 + 3][u] = hh_[3];
            }
        }
        __builtin_amdgcn_s_setprio(0);
    } else {
        // ---------------- E-waves: x-projection seed + staging ----------------
        const int wE   = w - 4;
        const int tidE = tid - 256;
        const int uE   = 16 * wE + col;
        const Frag2 w0 = load_wih_frag(Wih, bih, bhh, 0*HID + uE, quad, SNEG);
        const Frag2 w1 = load_wih_frag(Wih, bih, bhh, 1*HID + uE, quad, SNEG);
        const Frag2 w2 = load_wih_frag(Wih, bih, bhh, 2*HID + uE, quad, SPOS);
        const Frag2 w3 = load_wih_frag(Wih, bih, bhh, 3*HID + uE, quad, SNEG);

        {   // seed(0) — after initial barrier (xb staged), before first in-loop barrier
            bsh8 ax = xb[0][0][col];
            f32x4 e0 = {0.f,0.f,0.f,0.f}, e1 = e0, e2 = e0, e3 = e0;
            e0 = MFMA16(ax, w0.hi, e0); e0 = MFMA16(ax, w0.lo, e0);
            e1 = MFMA16(ax, w1.hi, e1); e1 = MFMA16(ax, w1.lo, e1);
            e2 = MFMA16(ax, w2.hi, e2); e2 = MFMA16(ax, w2.lo, e2);
            e3 = MFMA16(ax, w3.hi, e3); e3 = MFMA16(ax, w3.lo, e3);
            seedb[0][wE][0][lane] = e0;
            seedb[0][wE][1][lane] = e1;
            seedb[0][wE][2][lane] = e2;
            seedb[0][wE][3][lane] = e3;
        }
        for (int t = 0; t < TSTEPS; ++t) {
            __syncthreads();   // matches G's per-step barrier
            if ((t & 63) == 0 && t + 64 < TSTEPS)
                stage_chunk(feat, xb[((t >> 6) + 1) & 1], seq0, ((t >> 6) + 1) * 64, tidE);
            if (t + 1 < TSTEPS) {
                const int t1 = t + 1;
                bsh8 ax = xb[(t1 >> 6) & 1][t1 & 63][col];
                f32x4 e0 = {0.f,0.f,0.f,0.f}, e1 = e0, e2 = e0, e3 = e0;
                e0 = MFMA16(ax, w0.hi, e0); e0 = MFMA16(ax, w0.lo, e0);
                e1 = MFMA16(ax, w1.hi, e1); e1 = MFMA16(ax, w1.lo, e1);
                e2 = MFMA16(ax, w2.hi, e2); e2 = MFMA16(ax, w2.lo, e2);
                e3 = MFMA16(ax, w3.hi, e3); e3 = MFMA16(ax, w3.lo, e3);
                const int sb = t1 & 1;
                seedb[sb][wE][0][lane] = e0;
                seedb[sb][wE][1][lane] = e1;
                seedb[sb][wE][2][lane] = e2;
                seedb[sb][wE][3][lane] = e3;
            }
        }
    }
    __syncthreads();   // hf visible; E done

    // ---- fused pred head: pred = leaky_relu(h @ Wd^T + bd) ----
    if (tid < 256) {
        int s  = tid & 15;
        int hq = tid >> 4;           // 16 unit-groups of 4
        int j0 = hq * 4;
        float part = hf[s][j0] * Wd[j0] + hf[s][j0 + 1] * Wd[j0 + 1]
                   + hf[s][j0 + 2] * Wd[j0 + 2] + hf[s][j0 + 3] * Wd[j0 + 3];
        pf[s][hq] = part;
    }
    __syncthreads();
    if (tid < SPB) {
        float sum = bd[0];
#pragma unroll
        for (int j = 0; j < 16; ++j) sum += pf[tid][j];
        float p = (sum >= 0.0f) ? sum : 0.2f * sum;
        pred[seq0 + tid] = p;
    }
}

// fused losses: grid 512 (2 blocks/CU), 8 i-rows per block, f32x4 LDS reads.
// block 0 additionally does the masked-MSE partials.
__global__ __launch_bounds__(256)
void loss_kernel(const float* __restrict__ pred,
                 const float* __restrict__ ret,
                 const int* __restrict__ mask,
                 float* __restrict__ accums) {
    __shared__ __align__(16) float sp[NSEQ];
    __shared__ __align__(16) float sg[NSEQ];
    __shared__ __align__(16) float sq[NSEQ];
    __shared__ float wsum[8];
    int tid = threadIdx.x;
    for (int idx = tid; idx < NSEQ / 4; idx += 256) {
        f32x4 p4 = ((const f32x4*)pred)[idx];
        f32x4 g4 = ((const f32x4*)ret)[idx];
        i32x4 m4 = ((const i32x4*)mask)[idx];
        f32x4 q4;
#pragma unroll
        for (int l = 0; l < 4; ++l) q4[l] = m4[l] ? 1.0f : 0.0f;
        *(f32x4*)&sp[idx * 4] = p4;
        *(f32x4*)&sg[idx * 4] = g4;
        *(f32x4*)&sq[idx * 4] = q4;
    }
    __syncthreads();

    if (blockIdx.x == 0) {   // regression loss partials
        float v = 0.0f, m = 0.0f;
        for (int j = tid; j < NSEQ; j += 256) {
            float mj = sq[j];
            float d  = sp[j] - sg[j];
            v += d * d * mj;
            m += mj;
        }
#pragma unroll
        for (int off = 32; off > 0; off >>= 1) {
            v += __shfl_down(v, off, 64);
            m += __shfl_down(m, off, 64);
        }
        if ((tid & 63) == 0) {
            atomicAdd(&accums[0], v);
            atomicAdd(&accums[1], m);
        }
    }

    int iloc = tid >> 5;          // 8 rows per block
    int jp   = tid & 31;          // 32 lanes per row
    int i    = blockIdx.x * 8 + iloc;
    float pi = sp[i], gi = sg[i], qi = sq[i];
    float sum = 0.0f;
    for (int j0 = jp * 4; j0 < NSEQ; j0 += 128) {
        f32x4 p4 = *(const f32x4*)&sp[j0];
        f32x4 g4 = *(const f32x4*)&sg[j0];
        f32x4 q4 = *(const f32x4*)&sq[j0];
#pragma unroll
        for (int l = 0; l < 4; ++l) {
            float t = -(p4[l] - pi) * (g4[l] - gi);
            sum += fmaxf(t, 0.0f) * q4[l];
        }
    }
    sum *= qi;
#pragma unroll
    for (int off = 16; off > 0; off >>= 1) sum += __shfl_down(sum, off, 32);
    if (jp == 0) wsum[iloc] = sum;
    __syncthreads();
    if (tid == 0) {
        float s = wsum[0] + wsum[1] + wsum[2] + wsum[3]
                + wsum[4] + wsum[5] + wsum[6] + wsum[7];
        atomicAdd(&accums[2], s);
    }
}

__global__ void final_kernel(const float* __restrict__ accums,
                             float* __restrict__ out) {
    float reg  = accums[0] / (accums[1] + 1e-8f);
    float rank = accums[2] / 16777216.0f;   // N*N
    out[NSEQ + 0] = reg + rank;
    out[NSEQ + 1] = reg;
    out[NSEQ + 2] = rank;
}

extern "C" void kernel_launch(void* const* d_in, const int* in_sizes, int n_in,
                              void* d_out, int out_size, void* d_ws, size_t ws_size,
                              hipStream_t stream) {
    const float* feat = (const float*)d_in[0];
    const float* ret  = (const float*)d_in[1];
    const int*   mask = (const int*)d_in[2];
    const float* Wih  = (const float*)d_in[3];
    const float* Whh  = (const float*)d_in[4];
    const float* bih  = (const float*)d_in[5];
    const float* bhh  = (const float*)d_in[6];
    const float* Wd   = (const float*)d_in[7];
    const float* bd   = (const float*)d_in[8];
    float* out    = (float*)d_out;
    float* accums = (float*)d_ws;            // [0..3] loss partials

    lstm_kernel<<<NSEQ / SPB, BLK, 0, stream>>>(feat, Wih, Whh, bih, bhh,
                                                Wd, bd, out, accums);
    loss_kernel<<<NSEQ / 8, 256, 0, stream>>>(out, ret, mask, accums);
    final_kernel<<<1, 1, 0, stream>>>(accums, out);
}